// Round 1
// baseline (291.630 us; speedup 1.0000x reference)
//
#include <hip/hip_runtime.h>
#include <math.h>

// ---------------------------------------------------------------------------
// 2-layer GCN (PyG GCNConv semantics) on MI355X.
//   deg[c]  = #incoming edges + 1 (self loop); dinv = rsqrt(deg)
//   g       = bf16( dinv[n] * (X @ W) )     (MFMA GEMM + epilogue scale+pack)
//   out[c]  = dinv[c] * (g[c] + sum_{(r,c) in E} g[r]) + b   (CSR gather)
//   layer1: ReLU -> h1 (bf16); layer2: none, writes d_out (fp32).
// R9: CSR build via LDS-bucketed counting sort -- global atomics were the
//     limiter (25G/s issue-rate cap; split counters didn't move it, R8).
// R10: agg_kernel restructured edge-parallel: 2 nodes/wave (one per 32-lane
//     half), 32/Gp sub-groups per node each taking every SUBH-th edge, so a
//     whole avg-degree (16) neighbor list issues as ONE 16-edge in-flight
//     burst instead of two sequential 8-deep rounds; shfl_xor combine.
//     Old layout was latency-bound (VALU 28%, HBM 44%, occ 44%).
// Requires n <= 131072 (256-bucket LDS arrays in P1/P2); n = 100000 here.
// ---------------------------------------------------------------------------

#define BS 256
#define EPB 4096              // edges per P1/P2 block
#define BK_SHIFT 9            // 512 nodes per bucket

typedef __attribute__((ext_vector_type(8))) short bf16x8;
typedef __attribute__((ext_vector_type(4))) float f32x4;

union FragU {
    bf16x8 v;
    unsigned u[4];
};

__device__ __forceinline__ unsigned pack_bf16x2(float a, float b) {
    unsigned ua = __float_as_uint(a);
    unsigned ub = __float_as_uint(b);
    ua = (ua + 0x7fffu + ((ua >> 16) & 1u)) >> 16;   // RTE
    ub = (ub + 0x7fffu + ((ub >> 16) & 1u)) >> 16;
    return ua | (ub << 16);
}

__device__ __forceinline__ ushort bf16_rte(float a) {
    unsigned ua = __float_as_uint(a);
    return (ushort)((ua + 0x7fffu + ((ua >> 16) & 1u)) >> 16);
}

__device__ __forceinline__ float bf_lo(unsigned u) { return __uint_as_float(u << 16); }
__device__ __forceinline__ float bf_hi(unsigned u) { return __uint_as_float(u & 0xffff0000u); }

// P1: per-block LDS histogram over coarse buckets (col >> BK_SHIFT).
__global__ __launch_bounds__(BS) void p1_hist_kernel(const int* __restrict__ col,
                                                     int* __restrict__ countsT,
                                                     int E, int NBUCK, int NBLK) {
    __shared__ int h[256];
    int tid = threadIdx.x;
    h[tid] = 0;
    __syncthreads();
    int e0 = blockIdx.x * EPB;
    int e1 = min(e0 + EPB, E);
    for (int i = e0 + tid; i < e1; i += BS) atomicAdd(&h[col[i] >> BK_SHIFT], 1);
    __syncthreads();
    for (int b = tid; b < NBUCK; b += BS) countsT[b * NBLK + blockIdx.x] = h[b];
}

// generic block-exclusive scan (also used for countsT)
__global__ __launch_bounds__(BS) void scan_block_kernel(const int* __restrict__ in,
                                                        int* __restrict__ exc,
                                                        int* __restrict__ bsum, int N) {
    __shared__ int s[BS];
    int tid = threadIdx.x;
    int i = blockIdx.x * BS + tid;
    int v = (i < N) ? in[i] : 0;
    s[tid] = v;
    __syncthreads();
    for (int off = 1; off < BS; off <<= 1) {
        int t = (tid >= off) ? s[tid - off] : 0;
        __syncthreads();
        s[tid] += t;
        __syncthreads();
    }
    if (i < N) exc[i] = s[tid] - v;
    if (tid == BS - 1) bsum[blockIdx.x] = s[BS - 1];
}

__global__ __launch_bounds__(512) void scan_bsum_kernel(const int* __restrict__ bsum,
                                                        int* __restrict__ boff, int NB) {
    __shared__ int s[512];
    int tid = threadIdx.x;
    int v = (tid < NB) ? bsum[tid] : 0;
    s[tid] = v;
    __syncthreads();
    for (int off = 1; off < 512; off <<= 1) {
        int t = (tid >= off) ? s[tid - off] : 0;
        __syncthreads();
        s[tid] += t;
        __syncthreads();
    }
    if (tid < NB) boff[tid] = s[tid] - v;
}

__global__ __launch_bounds__(BS) void add_off_kernel(int* __restrict__ exc,
                                                     const int* __restrict__ boff, int N) {
    int i = blockIdx.x * BS + threadIdx.x;
    if (i < N) exc[i] += boff[blockIdx.x];
}

// P2: scatter edges into bucket-grouped pairs via LDS cursors.
__global__ __launch_bounds__(BS) void p2_scatter_kernel(const int* __restrict__ row,
                                                        const int* __restrict__ col,
                                                        const int* __restrict__ baseT,
                                                        uint2* __restrict__ pairs,
                                                        int E, int NBUCK, int NBLK) {
    __shared__ int cur[256];
    int tid = threadIdx.x;
    for (int b = tid; b < NBUCK; b += BS) cur[b] = baseT[b * NBLK + blockIdx.x];
    __syncthreads();
    int e0 = blockIdx.x * EPB;
    int e1 = min(e0 + EPB, E);
    for (int i = e0 + tid; i < e1; i += BS) {
        int c = col[i];
        int r = row[i];
        int pos = atomicAdd(&cur[c >> BK_SHIFT], 1);
        pairs[pos] = make_uint2((unsigned)r, (unsigned)c);
    }
}

// P3: per-bucket (512 nodes) LDS count + scan + place. Writes off/deg/dinv/src.
__global__ __launch_bounds__(BS) void p3_build_kernel(const uint2* __restrict__ pairs,
                                                      const int* __restrict__ baseT,
                                                      int* __restrict__ off_g,
                                                      int* __restrict__ deg_g,
                                                      float* __restrict__ dinv,
                                                      int* __restrict__ src,
                                                      int E, int n, int NBUCK, int NBLK) {
    __shared__ int cnt[512];
    __shared__ int scn[512];
    __shared__ int a256[256];
    int tid = threadIdx.x;
    int b = blockIdx.x;
    int s = baseT[b * NBLK];
    int eEnd = (b == NBUCK - 1) ? E : baseT[(b + 1) * NBLK];

    cnt[tid] = 0;
    cnt[tid + 256] = 0;
    __syncthreads();
    for (int i = s + tid; i < eEnd; i += BS) {
        uint2 p = pairs[i];
        atomicAdd(&cnt[p.y & 511], 1);
    }
    __syncthreads();
    int pairsum = cnt[2 * tid] + cnt[2 * tid + 1];
    a256[tid] = pairsum;
    __syncthreads();
    for (int off = 1; off < 256; off <<= 1) {
        int t = (tid >= off) ? a256[tid - off] : 0;
        __syncthreads();
        a256[tid] += t;
        __syncthreads();
    }
    int exc = a256[tid] - pairsum;
    scn[2 * tid] = exc;
    scn[2 * tid + 1] = exc + cnt[2 * tid];
    __syncthreads();
#pragma unroll
    for (int l = tid; l < 512; l += BS) {
        int node = (b << BK_SHIFT) + l;
        if (node < n) {
            off_g[node] = s + scn[l];
            deg_g[node] = cnt[l];
            dinv[node] = rsqrtf((float)(cnt[l] + 1));
        }
    }
    __syncthreads();
#pragma unroll
    for (int l = tid; l < 512; l += BS) scn[l] += s;   // cursors (global slots)
    __syncthreads();
    for (int i = s + tid; i < eEnd; i += BS) {
        uint2 p = pairs[i];
        int pos = atomicAdd(&scn[p.y & 511], 1);
        src[pos] = (int)p.x;
    }
}

// W^T-bf16 prep: wt1[n][k] = bf16(W1[k][n]) (128x128), wt2[n][k] = bf16(W2[k][n]) (64x128)
__global__ __launch_bounds__(BS) void wprep_kernel(const float* __restrict__ W1,
                                                   const float* __restrict__ W2,
                                                   ushort* __restrict__ wt1,
                                                   ushort* __restrict__ wt2) {
    int t = blockIdx.x * BS + threadIdx.x;
    if (t < 128 * 128) {
        int nn = t >> 7, k = t & 127;
        wt1[t] = bf16_rte(W1[k * 128 + nn]);
    }
    if (t < 64 * 128) {
        int nn = t >> 7, k = t & 127;
        wt2[t] = bf16_rte(W2[k * 64 + nn]);
    }
}

// G[m][ch] (bf16 packed) = bf16( dinv[m] * (A[m][128] @ W[128][NCH]) )
// MFMA 16x16x32, transposed: A-op = W^T (LDS, padded stride 136 shorts),
// B-op = A rows (global, fp32->bf16 in-reg if !IN_BF16).
template <int NCH, bool IN_BF16>
__global__ __launch_bounds__(BS) void gemm_mfma_kernel(const void* __restrict__ Ain,
                                                       const ushort* __restrict__ WT,
                                                       const float* __restrict__ dinv,
                                                       unsigned* __restrict__ G, int n) {
    constexpr int NT = NCH / 16;          // channel tiles
    constexpr int KP = 136;               // padded W^T row stride (shorts)
    __shared__ ushort wlds[NCH * KP];

    int tid = threadIdx.x;
    for (int c = tid; c < NCH * 16; c += BS) {
        int nr = c >> 4, q16 = c & 15;
        *(uint4*)(wlds + nr * KP + q16 * 8) = ((const uint4*)WT)[c];
    }
    __syncthreads();

    int lane = tid & 63, wv = tid >> 6;
    int ml = lane & 15, quad = lane >> 4;
    int m = blockIdx.x * 64 + wv * 16 + ml;

    FragU b[4];
    if (m < n) {
        if (IN_BF16) {
#pragma unroll
            for (int ks = 0; ks < 4; ++ks) {
                uint4 t = ((const uint4*)Ain)[(size_t)m * 16 + ks * 4 + quad];
                b[ks].u[0] = t.x; b[ks].u[1] = t.y; b[ks].u[2] = t.z; b[ks].u[3] = t.w;
            }
        } else {
            const float4* A = (const float4*)Ain + (size_t)m * 32;
#pragma unroll
            for (int ks = 0; ks < 4; ++ks) {
                float4 p0 = A[ks * 8 + quad * 2];
                float4 p1 = A[ks * 8 + quad * 2 + 1];
                b[ks].u[0] = pack_bf16x2(p0.x, p0.y);
                b[ks].u[1] = pack_bf16x2(p0.z, p0.w);
                b[ks].u[2] = pack_bf16x2(p1.x, p1.y);
                b[ks].u[3] = pack_bf16x2(p1.z, p1.w);
            }
        }
    } else {
#pragma unroll
        for (int ks = 0; ks < 4; ++ks) {
            b[ks].u[0] = 0; b[ks].u[1] = 0; b[ks].u[2] = 0; b[ks].u[3] = 0;
        }
    }

    f32x4 acc[NT];
#pragma unroll
    for (int nt = 0; nt < NT; ++nt) {
        acc[nt][0] = 0.f; acc[nt][1] = 0.f; acc[nt][2] = 0.f; acc[nt][3] = 0.f;
    }

#pragma unroll
    for (int nt = 0; nt < NT; ++nt) {
#pragma unroll
        for (int ks = 0; ks < 4; ++ks) {
            bf16x8 a = *(const bf16x8*)(wlds + (nt * 16 + ml) * KP + ks * 32 + quad * 8);
            acc[nt] = __builtin_amdgcn_mfma_f32_16x16x32_bf16(a, b[ks].v, acc[nt], 0, 0, 0);
        }
    }

    if (m < n) {
        float dv = dinv[m];
        unsigned* grow = G + (size_t)m * (NCH / 2);
#pragma unroll
        for (int nt = 0; nt < NT; ++nt) {
            uint2 o;
            o.x = pack_bf16x2(acc[nt][0] * dv, acc[nt][1] * dv);
            o.y = pack_bf16x2(acc[nt][2] * dv, acc[nt][3] * dv);
            *(uint2*)(grow + nt * 8 + quad * 2) = o;
        }
    }
}

// out[node][c] = act( dinv[node] * (G[node][c] + sum_{s in CSR(node)} G[s][c]) + b[c] )
// G bf16-packed; each lane covers 8 channels (one uint4).
// R10 layout: 2 nodes per wave (one per 32-lane half). Within a half,
// SUBH = 32/Gp sub-groups each take every SUBH-th edge; the main loop issues
// 16 edges per node (32 per wave) as ONE in-flight burst, so an avg-degree
// node's entire gather overlaps instead of two sequential 8-deep rounds.
// Partials combined with shfl_xor; q==0 lanes write the row.
template <int C, bool RELU, bool OUT_BF16>
__global__ __launch_bounds__(BS) void agg_kernel(const unsigned* __restrict__ G,
                                                 const int* __restrict__ edge_off,
                                                 const int* __restrict__ cnt,
                                                 const int* __restrict__ src,
                                                 const float* __restrict__ dinv,
                                                 const float* __restrict__ bias,
                                                 void* __restrict__ out, int n) {
    constexpr int Gp = C / 8;             // uint4 lanes per row (16 or 8)
    constexpr int SUBH = 32 / Gp;         // edge sub-groups per half-wave (2 or 4)
    constexpr int UN = 16 / SUBH;         // unrolled edges per sub-group (8 or 4)
    constexpr int GSH = (Gp == 16) ? 4 : 3;

    int tid = threadIdx.x;
    int lane = tid & 63;
    int cl = lane & (Gp - 1);                 // channel lane within sub-group
    int q = (lane >> GSH) & (SUBH - 1);       // sub-group index within half
    int node = blockIdx.x * (BS / 32) + (tid >> 5);   // 8 nodes per block
    if (node >= n) return;

    const uint4* G4 = (const uint4*)G;
    const int* sp = src + edge_off[node];
    int deg = cnt[node];

    float acc[8];
    if (q == 0) {
        uint4 sv = G4[(size_t)node * Gp + cl];   // self-loop term
        acc[0] = bf_lo(sv.x); acc[1] = bf_hi(sv.x);
        acc[2] = bf_lo(sv.y); acc[3] = bf_hi(sv.y);
        acc[4] = bf_lo(sv.z); acc[5] = bf_hi(sv.z);
        acc[6] = bf_lo(sv.w); acc[7] = bf_hi(sv.w);
    } else {
#pragma unroll
        for (int k = 0; k < 8; ++k) acc[k] = 0.f;
    }

#define ACCUM(v)                                                               \
    acc[0] += bf_lo(v.x); acc[1] += bf_hi(v.x);                                \
    acc[2] += bf_lo(v.y); acc[3] += bf_hi(v.y);                                \
    acc[4] += bf_lo(v.z); acc[5] += bf_hi(v.z);                                \
    acc[6] += bf_lo(v.w); acc[7] += bf_hi(v.w);

    int i = 0;
    // main burst: 16 edges per node per iteration, all loads issued together
    for (; i + 16 <= deg; i += 16) {
        int s[UN];
#pragma unroll
        for (int u = 0; u < UN; ++u) s[u] = sp[i + q + SUBH * u];
        uint4 v[UN];
#pragma unroll
        for (int u = 0; u < UN; ++u) v[u] = G4[(size_t)s[u] * Gp + cl];
#pragma unroll
        for (int u = 0; u < UN; ++u) { ACCUM(v[u]) }
    }
    // mid: SUBH edges per iteration (one per sub-group)
    for (; i + SUBH <= deg; i += SUBH) {
        int s0 = sp[i + q];
        uint4 v0 = G4[(size_t)s0 * Gp + cl];
        ACCUM(v0)
    }
    // tail: fewer than SUBH edges remain
    if (i < deg && q < deg - i) {
        int s0 = sp[i + q];
        uint4 v0 = G4[(size_t)s0 * Gp + cl];
        ACCUM(v0)
    }
#undef ACCUM

    // combine sub-group partials within the 32-lane half
#pragma unroll
    for (int k = 0; k < 8; ++k) {
        if constexpr (SUBH == 4) acc[k] += __shfl_xor(acc[k], 8, 64);
        acc[k] += __shfl_xor(acc[k], 16, 64);
    }
    if (q != 0) return;

    float dv = dinv[node];
    const float4* b4 = (const float4*)bias;
    float4 bl = b4[2 * cl + 0], bh = b4[2 * cl + 1];
    float o0x = acc[0] * dv + bl.x, o0y = acc[1] * dv + bl.y;
    float o0z = acc[2] * dv + bl.z, o0w = acc[3] * dv + bl.w;
    float o1x = acc[4] * dv + bh.x, o1y = acc[5] * dv + bh.y;
    float o1z = acc[6] * dv + bh.z, o1w = acc[7] * dv + bh.w;
    if (RELU) {
        o0x = fmaxf(o0x, 0.f); o0y = fmaxf(o0y, 0.f);
        o0z = fmaxf(o0z, 0.f); o0w = fmaxf(o0w, 0.f);
        o1x = fmaxf(o1x, 0.f); o1y = fmaxf(o1y, 0.f);
        o1z = fmaxf(o1z, 0.f); o1w = fmaxf(o1w, 0.f);
    }
    if (OUT_BF16) {
        uint4 ov;
        ov.x = pack_bf16x2(o0x, o0y);
        ov.y = pack_bf16x2(o0z, o0w);
        ov.z = pack_bf16x2(o1x, o1y);
        ov.w = pack_bf16x2(o1z, o1w);
        ((uint4*)out)[(size_t)node * Gp + cl] = ov;
    } else {
        float4* orow = (float4*)((float*)out + (size_t)node * C);
        orow[2 * cl + 0] = make_float4(o0x, o0y, o0z, o0w);
        orow[2 * cl + 1] = make_float4(o1x, o1y, o1z, o1w);
    }
}

extern "C" void kernel_launch(void* const* d_in, const int* in_sizes, int n_in,
                              void* d_out, int out_size, void* d_ws, size_t ws_size,
                              hipStream_t stream) {
    const float* x  = (const float*)d_in[0];
    const int*   ei = (const int*)d_in[1];      // [2, E] int32
    const float* W1 = (const float*)d_in[2];
    const float* b1 = (const float*)d_in[3];
    const float* W2 = (const float*)d_in[4];
    const float* b2 = (const float*)d_in[5];

    const int IN_C = 128, HID_C = 128;
    int n = in_sizes[0] / IN_C;
    int E = in_sizes[1] / 2;
    const int* row = ei;
    const int* col = ei + E;

    int NBUCK = (n + 511) >> BK_SHIFT;          // coarse buckets (<=256 for n<=128k)
    int NBLK = (E + EPB - 1) / EPB;             // P1/P2 blocks
    int M = NBUCK * NBLK;                       // countsT entries
    int NBS = (M + BS - 1) / BS;                // scan blocks (<=512)

    char* w = (char*)d_ws;
    auto alloc = [&](size_t bytes) {
        void* p = (void*)w;
        w += (bytes + 255) & ~(size_t)255;
        return p;
    };
    int*      countsT = (int*)alloc((size_t)M * 4);
    int*      baseT   = (int*)alloc((size_t)M * 4);
    int*      bsum    = (int*)alloc((size_t)NBS * 4);
    int*      boff    = (int*)alloc((size_t)NBS * 4);
    uint2*    pairs   = (uint2*)alloc((size_t)E * 8);
    int*      src     = (int*)alloc((size_t)E * 4);
    int*      off     = (int*)alloc((size_t)n * 4);
    int*      deg     = (int*)alloc((size_t)n * 4);
    float*    dinv    = (float*)alloc((size_t)n * 4);
    ushort*   wt1     = (ushort*)alloc(128 * 128 * 2);
    ushort*   wt2     = (ushort*)alloc(64 * 128 * 2);
    unsigned* g       = (unsigned*)alloc((size_t)n * HID_C * 2);  // bf16-packed
    unsigned* h1b     = (unsigned*)alloc((size_t)n * HID_C * 2);  // bf16-packed h1

    // W^T-bf16 prep (independent)
    wprep_kernel<<<64, BS, 0, stream>>>(W1, W2, wt1, wt2);

    // CSR build: LDS-bucketed counting sort (no global atomics)
    p1_hist_kernel<<<NBLK, BS, 0, stream>>>(col, countsT, E, NBUCK, NBLK);
    scan_block_kernel<<<NBS, BS, 0, stream>>>(countsT, baseT, bsum, M);
    scan_bsum_kernel<<<1, 512, 0, stream>>>(bsum, boff, NBS);
    add_off_kernel<<<NBS, BS, 0, stream>>>(baseT, boff, M);
    p2_scatter_kernel<<<NBLK, BS, 0, stream>>>(row, col, baseT, pairs, E, NBUCK, NBLK);
    p3_build_kernel<<<NBUCK, BS, 0, stream>>>(pairs, baseT, off, deg, dinv, src,
                                              E, n, NBUCK, NBLK);

    int gridM = (n + 63) / 64;

    // layer 1: g = bf16(dinv * (x @ W1)); h1b = bf16(relu(dinv*(self+gather)+b1))
    gemm_mfma_kernel<128, false><<<gridM, BS, 0, stream>>>(x, wt1, dinv, g, n);
    agg_kernel<128, true, true><<<(n + 7) / 8, BS, 0, stream>>>(g, off, deg, src,
                                                                dinv, b1, h1b, n);

    // layer 2: g2 = bf16(dinv * (h1 @ W2)); out = dinv*(self+gather) + b2 (fp32)
    gemm_mfma_kernel<64, true><<<gridM, BS, 0, stream>>>(h1b, wt2, dinv, g, n);
    agg_kernel<64, false, false><<<(n + 7) / 8, BS, 0, stream>>>(g, off, deg, src,
                                                                 dinv, b2, d_out, n);
}

// Round 3
// 276.396 us; speedup vs baseline: 1.0551x; 1.0551x over previous
//
#include <hip/hip_runtime.h>
#include <math.h>

// ---------------------------------------------------------------------------
// 2-layer GCN (PyG GCNConv semantics) on MI355X.
//   deg[c]  = #incoming edges + 1 (self loop); dinv = rsqrt(deg)
//   g       = bf16( dinv[n] * (X @ W) )     (MFMA GEMM + epilogue scale+pack)
//   out[c]  = dinv[c] * (g[c] + sum_{(r,c) in E} g[r]) + b   (CSR gather)
//   layer1: ReLU -> h1 (bf16); layer2: none, writes d_out (fp32).
// R9: CSR build via LDS-bucketed counting sort (no global atomics).
// R10 (REVERTED): edge-parallel 2-node/wave split regressed 61.6->80.2 us:
//     its mid loop was only 2 edges/dependent-round, and ~half the Poisson(16)
//     degree mass is <16 -- average chained rounds per node went UP.
// R11: R0 structure (Gp lanes/node, 8-deep row bursts) plus:
//     (a) cooperative index prefetch: ONE vector load grabs Gp indices
//         (lane l -> sp[i+l]), broadcast via __shfl -- halves dependent
//         memory rounds per chunk vs per-burst index loads;
//     (b) graduated tail ladder 8/4/2/1 with shfl'd indices (no wasted rows);
//     (c) nontemporal hints on streamed-once src reads + output stores to
//         keep L2 capacity for the reused G table.
// R12: compile fix -- nontemporal builtins need clang ext-vector types, not
//     HIP_vector_type (uint4/float4). Stores now go through u32x4/f32x4.
// Requires n <= 131072 (256-bucket LDS arrays in P1/P2); n = 100000 here.
// ---------------------------------------------------------------------------

#define BS 256
#define EPB 4096              // edges per P1/P2 block
#define BK_SHIFT 9            // 512 nodes per bucket

typedef __attribute__((ext_vector_type(8))) short bf16x8;
typedef __attribute__((ext_vector_type(4))) float f32x4;
typedef __attribute__((ext_vector_type(4))) unsigned u32x4;

union FragU {
    bf16x8 v;
    unsigned u[4];
};

__device__ __forceinline__ unsigned pack_bf16x2(float a, float b) {
    unsigned ua = __float_as_uint(a);
    unsigned ub = __float_as_uint(b);
    ua = (ua + 0x7fffu + ((ua >> 16) & 1u)) >> 16;   // RTE
    ub = (ub + 0x7fffu + ((ub >> 16) & 1u)) >> 16;
    return ua | (ub << 16);
}

__device__ __forceinline__ ushort bf16_rte(float a) {
    unsigned ua = __float_as_uint(a);
    return (ushort)((ua + 0x7fffu + ((ua >> 16) & 1u)) >> 16);
}

__device__ __forceinline__ float bf_lo(unsigned u) { return __uint_as_float(u << 16); }
__device__ __forceinline__ float bf_hi(unsigned u) { return __uint_as_float(u & 0xffff0000u); }

// P1: per-block LDS histogram over coarse buckets (col >> BK_SHIFT).
__global__ __launch_bounds__(BS) void p1_hist_kernel(const int* __restrict__ col,
                                                     int* __restrict__ countsT,
                                                     int E, int NBUCK, int NBLK) {
    __shared__ int h[256];
    int tid = threadIdx.x;
    h[tid] = 0;
    __syncthreads();
    int e0 = blockIdx.x * EPB;
    int e1 = min(e0 + EPB, E);
    for (int i = e0 + tid; i < e1; i += BS) atomicAdd(&h[col[i] >> BK_SHIFT], 1);
    __syncthreads();
    for (int b = tid; b < NBUCK; b += BS) countsT[b * NBLK + blockIdx.x] = h[b];
}

// generic block-exclusive scan (also used for countsT)
__global__ __launch_bounds__(BS) void scan_block_kernel(const int* __restrict__ in,
                                                        int* __restrict__ exc,
                                                        int* __restrict__ bsum, int N) {
    __shared__ int s[BS];
    int tid = threadIdx.x;
    int i = blockIdx.x * BS + tid;
    int v = (i < N) ? in[i] : 0;
    s[tid] = v;
    __syncthreads();
    for (int off = 1; off < BS; off <<= 1) {
        int t = (tid >= off) ? s[tid - off] : 0;
        __syncthreads();
        s[tid] += t;
        __syncthreads();
    }
    if (i < N) exc[i] = s[tid] - v;
    if (tid == BS - 1) bsum[blockIdx.x] = s[BS - 1];
}

__global__ __launch_bounds__(512) void scan_bsum_kernel(const int* __restrict__ bsum,
                                                        int* __restrict__ boff, int NB) {
    __shared__ int s[512];
    int tid = threadIdx.x;
    int v = (tid < NB) ? bsum[tid] : 0;
    s[tid] = v;
    __syncthreads();
    for (int off = 1; off < 512; off <<= 1) {
        int t = (tid >= off) ? s[tid - off] : 0;
        __syncthreads();
        s[tid] += t;
        __syncthreads();
    }
    if (tid < NB) boff[tid] = s[tid] - v;
}

__global__ __launch_bounds__(BS) void add_off_kernel(int* __restrict__ exc,
                                                     const int* __restrict__ boff, int N) {
    int i = blockIdx.x * BS + threadIdx.x;
    if (i < N) exc[i] += boff[blockIdx.x];
}

// P2: scatter edges into bucket-grouped pairs via LDS cursors.
__global__ __launch_bounds__(BS) void p2_scatter_kernel(const int* __restrict__ row,
                                                        const int* __restrict__ col,
                                                        const int* __restrict__ baseT,
                                                        uint2* __restrict__ pairs,
                                                        int E, int NBUCK, int NBLK) {
    __shared__ int cur[256];
    int tid = threadIdx.x;
    for (int b = tid; b < NBUCK; b += BS) cur[b] = baseT[b * NBLK + blockIdx.x];
    __syncthreads();
    int e0 = blockIdx.x * EPB;
    int e1 = min(e0 + EPB, E);
    for (int i = e0 + tid; i < e1; i += BS) {
        int c = col[i];
        int r = row[i];
        int pos = atomicAdd(&cur[c >> BK_SHIFT], 1);
        pairs[pos] = make_uint2((unsigned)r, (unsigned)c);
    }
}

// P3: per-bucket (512 nodes) LDS count + scan + place. Writes off/deg/dinv/src.
__global__ __launch_bounds__(BS) void p3_build_kernel(const uint2* __restrict__ pairs,
                                                      const int* __restrict__ baseT,
                                                      int* __restrict__ off_g,
                                                      int* __restrict__ deg_g,
                                                      float* __restrict__ dinv,
                                                      int* __restrict__ src,
                                                      int E, int n, int NBUCK, int NBLK) {
    __shared__ int cnt[512];
    __shared__ int scn[512];
    __shared__ int a256[256];
    int tid = threadIdx.x;
    int b = blockIdx.x;
    int s = baseT[b * NBLK];
    int eEnd = (b == NBUCK - 1) ? E : baseT[(b + 1) * NBLK];

    cnt[tid] = 0;
    cnt[tid + 256] = 0;
    __syncthreads();
    for (int i = s + tid; i < eEnd; i += BS) {
        uint2 p = pairs[i];
        atomicAdd(&cnt[p.y & 511], 1);
    }
    __syncthreads();
    int pairsum = cnt[2 * tid] + cnt[2 * tid + 1];
    a256[tid] = pairsum;
    __syncthreads();
    for (int off = 1; off < 256; off <<= 1) {
        int t = (tid >= off) ? a256[tid - off] : 0;
        __syncthreads();
        a256[tid] += t;
        __syncthreads();
    }
    int exc = a256[tid] - pairsum;
    scn[2 * tid] = exc;
    scn[2 * tid + 1] = exc + cnt[2 * tid];
    __syncthreads();
#pragma unroll
    for (int l = tid; l < 512; l += BS) {
        int node = (b << BK_SHIFT) + l;
        if (node < n) {
            off_g[node] = s + scn[l];
            deg_g[node] = cnt[l];
            dinv[node] = rsqrtf((float)(cnt[l] + 1));
        }
    }
    __syncthreads();
#pragma unroll
    for (int l = tid; l < 512; l += BS) scn[l] += s;   // cursors (global slots)
    __syncthreads();
    for (int i = s + tid; i < eEnd; i += BS) {
        uint2 p = pairs[i];
        int pos = atomicAdd(&scn[p.y & 511], 1);
        src[pos] = (int)p.x;
    }
}

// W^T-bf16 prep: wt1[n][k] = bf16(W1[k][n]) (128x128), wt2[n][k] = bf16(W2[k][n]) (64x128)
__global__ __launch_bounds__(BS) void wprep_kernel(const float* __restrict__ W1,
                                                   const float* __restrict__ W2,
                                                   ushort* __restrict__ wt1,
                                                   ushort* __restrict__ wt2) {
    int t = blockIdx.x * BS + threadIdx.x;
    if (t < 128 * 128) {
        int nn = t >> 7, k = t & 127;
        wt1[t] = bf16_rte(W1[k * 128 + nn]);
    }
    if (t < 64 * 128) {
        int nn = t >> 7, k = t & 127;
        wt2[t] = bf16_rte(W2[k * 64 + nn]);
    }
}

// G[m][ch] (bf16 packed) = bf16( dinv[m] * (A[m][128] @ W[128][NCH]) )
// MFMA 16x16x32, transposed: A-op = W^T (LDS, padded stride 136 shorts),
// B-op = A rows (global, fp32->bf16 in-reg if !IN_BF16).
template <int NCH, bool IN_BF16>
__global__ __launch_bounds__(BS) void gemm_mfma_kernel(const void* __restrict__ Ain,
                                                       const ushort* __restrict__ WT,
                                                       const float* __restrict__ dinv,
                                                       unsigned* __restrict__ G, int n) {
    constexpr int NT = NCH / 16;          // channel tiles
    constexpr int KP = 136;               // padded W^T row stride (shorts)
    __shared__ ushort wlds[NCH * KP];

    int tid = threadIdx.x;
    for (int c = tid; c < NCH * 16; c += BS) {
        int nr = c >> 4, q16 = c & 15;
        *(uint4*)(wlds + nr * KP + q16 * 8) = ((const uint4*)WT)[c];
    }
    __syncthreads();

    int lane = tid & 63, wv = tid >> 6;
    int ml = lane & 15, quad = lane >> 4;
    int m = blockIdx.x * 64 + wv * 16 + ml;

    FragU b[4];
    if (m < n) {
        if (IN_BF16) {
#pragma unroll
            for (int ks = 0; ks < 4; ++ks) {
                uint4 t = ((const uint4*)Ain)[(size_t)m * 16 + ks * 4 + quad];
                b[ks].u[0] = t.x; b[ks].u[1] = t.y; b[ks].u[2] = t.z; b[ks].u[3] = t.w;
            }
        } else {
            const float4* A = (const float4*)Ain + (size_t)m * 32;
#pragma unroll
            for (int ks = 0; ks < 4; ++ks) {
                float4 p0 = A[ks * 8 + quad * 2];
                float4 p1 = A[ks * 8 + quad * 2 + 1];
                b[ks].u[0] = pack_bf16x2(p0.x, p0.y);
                b[ks].u[1] = pack_bf16x2(p0.z, p0.w);
                b[ks].u[2] = pack_bf16x2(p1.x, p1.y);
                b[ks].u[3] = pack_bf16x2(p1.z, p1.w);
            }
        }
    } else {
#pragma unroll
        for (int ks = 0; ks < 4; ++ks) {
            b[ks].u[0] = 0; b[ks].u[1] = 0; b[ks].u[2] = 0; b[ks].u[3] = 0;
        }
    }

    f32x4 acc[NT];
#pragma unroll
    for (int nt = 0; nt < NT; ++nt) {
        acc[nt][0] = 0.f; acc[nt][1] = 0.f; acc[nt][2] = 0.f; acc[nt][3] = 0.f;
    }

#pragma unroll
    for (int nt = 0; nt < NT; ++nt) {
#pragma unroll
        for (int ks = 0; ks < 4; ++ks) {
            bf16x8 a = *(const bf16x8*)(wlds + (nt * 16 + ml) * KP + ks * 32 + quad * 8);
            acc[nt] = __builtin_amdgcn_mfma_f32_16x16x32_bf16(a, b[ks].v, acc[nt], 0, 0, 0);
        }
    }

    if (m < n) {
        float dv = dinv[m];
        unsigned* grow = G + (size_t)m * (NCH / 2);
#pragma unroll
        for (int nt = 0; nt < NT; ++nt) {
            uint2 o;
            o.x = pack_bf16x2(acc[nt][0] * dv, acc[nt][1] * dv);
            o.y = pack_bf16x2(acc[nt][2] * dv, acc[nt][3] * dv);
            *(uint2*)(grow + nt * 8 + quad * 2) = o;
        }
    }
}

// out[node][c] = act( dinv[node] * (G[node][c] + sum_{s in CSR(node)} G[s][c]) + b[c] )
// G bf16-packed; each lane covers 8 channels (one uint4).
// R11: Gp lanes per node (R0 structure). Main loop: per Gp-edge chunk,
// ONE cooperative index load (lane l -> sp[i+l]) + shfl broadcast, then
// 8-deep row bursts. Tail: 8/4/2/1 ladder with shfl'd indices. nt hints on
// src reads + output stores keep L2 for the reused G table.
template <int C, bool RELU, bool OUT_BF16>
__global__ __launch_bounds__(BS) void agg_kernel(const unsigned* __restrict__ G,
                                                 const int* __restrict__ edge_off,
                                                 const int* __restrict__ cnt,
                                                 const int* __restrict__ src,
                                                 const float* __restrict__ dinv,
                                                 const float* __restrict__ bias,
                                                 void* __restrict__ out, int n) {
    constexpr int Gp = C / 8;          // uint4 lanes per node (16 or 8)
    constexpr int NPB = BS / Gp;       // nodes per block
    int lane = threadIdx.x & (Gp - 1);
    int li = threadIdx.x / Gp;
    int node = blockIdx.x * NPB + li;
    if (node >= n) return;

    const uint4* G4 = (const uint4*)G;
    float acc[8];
    {
        uint4 sv = G4[(size_t)node * Gp + lane];   // self-loop term
        acc[0] = bf_lo(sv.x); acc[1] = bf_hi(sv.x);
        acc[2] = bf_lo(sv.y); acc[3] = bf_hi(sv.y);
        acc[4] = bf_lo(sv.z); acc[5] = bf_hi(sv.z);
        acc[6] = bf_lo(sv.w); acc[7] = bf_hi(sv.w);
    }
    const int* sp = src + edge_off[node];
    int deg = cnt[node];

#define ACCUM(v)                                                               \
    acc[0] += bf_lo(v.x); acc[1] += bf_hi(v.x);                                \
    acc[2] += bf_lo(v.y); acc[3] += bf_hi(v.y);                                \
    acc[4] += bf_lo(v.z); acc[5] += bf_hi(v.z);                                \
    acc[6] += bf_lo(v.w); acc[7] += bf_hi(v.w);

    int i = 0;
    // main: Gp-edge chunks; 1 cooperative idx load + shfl, 8-deep row bursts
    for (; i + Gp <= deg; i += Gp) {
        int myi = __builtin_nontemporal_load(sp + i + lane);
#pragma unroll
        for (int h = 0; h < Gp / 8; ++h) {
            uint4 v[8];
#pragma unroll
            for (int u = 0; u < 8; ++u) {
                int s = __shfl(myi, h * 8 + u, Gp);
                v[u] = G4[(size_t)s * Gp + lane];
            }
#pragma unroll
            for (int u = 0; u < 8; ++u) { ACCUM(v[u]) }
        }
    }
    // tail: rem < Gp edges, graduated 8/4/2/1 ladder (indices via shfl)
    int rem = deg - i;
    if (rem > 0) {
        int myi = (lane < rem) ? __builtin_nontemporal_load(sp + i + lane) : 0;
        int j = 0;
        if (Gp == 16 && rem >= 8) {
            uint4 v[8];
#pragma unroll
            for (int u = 0; u < 8; ++u) {
                int s = __shfl(myi, u, Gp);
                v[u] = G4[(size_t)s * Gp + lane];
            }
#pragma unroll
            for (int u = 0; u < 8; ++u) { ACCUM(v[u]) }
            j = 8;
        }
        if (rem - j >= 4) {
            uint4 v[4];
#pragma unroll
            for (int u = 0; u < 4; ++u) {
                int s = __shfl(myi, j + u, Gp);
                v[u] = G4[(size_t)s * Gp + lane];
            }
#pragma unroll
            for (int u = 0; u < 4; ++u) { ACCUM(v[u]) }
            j += 4;
        }
        if (rem - j >= 2) {
            uint4 v0, v1;
            {
                int s0 = __shfl(myi, j, Gp);
                int s1 = __shfl(myi, j + 1, Gp);
                v0 = G4[(size_t)s0 * Gp + lane];
                v1 = G4[(size_t)s1 * Gp + lane];
            }
            ACCUM(v0) ACCUM(v1)
            j += 2;
        }
        if (rem - j >= 1) {
            int s0 = __shfl(myi, j, Gp);
            uint4 v0 = G4[(size_t)s0 * Gp + lane];
            ACCUM(v0)
        }
    }
#undef ACCUM

    float dv = dinv[node];
    const float4* b4 = (const float4*)bias;
    float4 bl = b4[2 * lane + 0], bh = b4[2 * lane + 1];
    float o0x = acc[0] * dv + bl.x, o0y = acc[1] * dv + bl.y;
    float o0z = acc[2] * dv + bl.z, o0w = acc[3] * dv + bl.w;
    float o1x = acc[4] * dv + bh.x, o1y = acc[5] * dv + bh.y;
    float o1z = acc[6] * dv + bh.z, o1w = acc[7] * dv + bh.w;
    if (RELU) {
        o0x = fmaxf(o0x, 0.f); o0y = fmaxf(o0y, 0.f);
        o0z = fmaxf(o0z, 0.f); o0w = fmaxf(o0w, 0.f);
        o1x = fmaxf(o1x, 0.f); o1y = fmaxf(o1y, 0.f);
        o1z = fmaxf(o1z, 0.f); o1w = fmaxf(o1w, 0.f);
    }
    if (OUT_BF16) {
        u32x4 ov;
        ov.x = pack_bf16x2(o0x, o0y);
        ov.y = pack_bf16x2(o0z, o0w);
        ov.z = pack_bf16x2(o1x, o1y);
        ov.w = pack_bf16x2(o1z, o1w);
        __builtin_nontemporal_store(ov, (u32x4*)out + (size_t)node * Gp + lane);
    } else {
        f32x4* orow = (f32x4*)((float*)out + (size_t)node * C);
        f32x4 o0; o0.x = o0x; o0.y = o0y; o0.z = o0z; o0.w = o0w;
        f32x4 o1; o1.x = o1x; o1.y = o1y; o1.z = o1z; o1.w = o1w;
        __builtin_nontemporal_store(o0, orow + 2 * lane + 0);
        __builtin_nontemporal_store(o1, orow + 2 * lane + 1);
    }
}

extern "C" void kernel_launch(void* const* d_in, const int* in_sizes, int n_in,
                              void* d_out, int out_size, void* d_ws, size_t ws_size,
                              hipStream_t stream) {
    const float* x  = (const float*)d_in[0];
    const int*   ei = (const int*)d_in[1];      // [2, E] int32
    const float* W1 = (const float*)d_in[2];
    const float* b1 = (const float*)d_in[3];
    const float* W2 = (const float*)d_in[4];
    const float* b2 = (const float*)d_in[5];

    const int IN_C = 128, HID_C = 128;
    int n = in_sizes[0] / IN_C;
    int E = in_sizes[1] / 2;
    const int* row = ei;
    const int* col = ei + E;

    int NBUCK = (n + 511) >> BK_SHIFT;          // coarse buckets (<=256 for n<=128k)
    int NBLK = (E + EPB - 1) / EPB;             // P1/P2 blocks
    int M = NBUCK * NBLK;                       // countsT entries
    int NBS = (M + BS - 1) / BS;                // scan blocks (<=512)

    char* w = (char*)d_ws;
    auto alloc = [&](size_t bytes) {
        void* p = (void*)w;
        w += (bytes + 255) & ~(size_t)255;
        return p;
    };
    int*      countsT = (int*)alloc((size_t)M * 4);
    int*      baseT   = (int*)alloc((size_t)M * 4);
    int*      bsum    = (int*)alloc((size_t)NBS * 4);
    int*      boff    = (int*)alloc((size_t)NBS * 4);
    uint2*    pairs   = (uint2*)alloc((size_t)E * 8);
    int*      src     = (int*)alloc((size_t)E * 4);
    int*      off     = (int*)alloc((size_t)n * 4);
    int*      deg     = (int*)alloc((size_t)n * 4);
    float*    dinv    = (float*)alloc((size_t)n * 4);
    ushort*   wt1     = (ushort*)alloc(128 * 128 * 2);
    ushort*   wt2     = (ushort*)alloc(64 * 128 * 2);
    unsigned* g       = (unsigned*)alloc((size_t)n * HID_C * 2);  // bf16-packed
    unsigned* h1b     = (unsigned*)alloc((size_t)n * HID_C * 2);  // bf16-packed h1

    // W^T-bf16 prep (independent)
    wprep_kernel<<<64, BS, 0, stream>>>(W1, W2, wt1, wt2);

    // CSR build: LDS-bucketed counting sort (no global atomics)
    p1_hist_kernel<<<NBLK, BS, 0, stream>>>(col, countsT, E, NBUCK, NBLK);
    scan_block_kernel<<<NBS, BS, 0, stream>>>(countsT, baseT, bsum, M);
    scan_bsum_kernel<<<1, 512, 0, stream>>>(bsum, boff, NBS);
    add_off_kernel<<<NBS, BS, 0, stream>>>(baseT, boff, M);
    p2_scatter_kernel<<<NBLK, BS, 0, stream>>>(row, col, baseT, pairs, E, NBUCK, NBLK);
    p3_build_kernel<<<NBUCK, BS, 0, stream>>>(pairs, baseT, off, deg, dinv, src,
                                              E, n, NBUCK, NBLK);

    int gridM = (n + 63) / 64;

    // layer 1: g = bf16(dinv * (x @ W1)); h1b = bf16(relu(dinv*(self+gather)+b1))
    gemm_mfma_kernel<128, false><<<gridM, BS, 0, stream>>>(x, wt1, dinv, g, n);
    agg_kernel<128, true, true><<<(n + 15) / 16, BS, 0, stream>>>(g, off, deg, src,
                                                                  dinv, b1, h1b, n);

    // layer 2: g2 = bf16(dinv * (h1 @ W2)); out = dinv*(self+gather) + b2 (fp32)
    gemm_mfma_kernel<64, true><<<gridM, BS, 0, stream>>>(h1b, wt2, dinv, g, n);
    agg_kernel<64, false, false><<<(n + 31) / 32, BS, 0, stream>>>(g, off, deg, src,
                                                                   dinv, b2, d_out, n);
}